// Round 1
// 5613.361 us; speedup vs baseline: 1.6754x; 1.6754x over previous
//
#include <hip/hip_runtime.h>
#include <math.h>

// GPT forward: L=4, H=12, E=768, HS=64, V=32000, B=2, T=1024
// Inputs (f32 unless noted):
// 0 idx(i32) 1 targets(i32) 2 tok_emb 3 pos_emb 4 Wq 5 bq 6 Wk 7 bk 8 Wv 9 bv
// 10 Wo 11 bo 12 ln1_g 13 ln1_b 14 W1 15 b1 16 W2 17 b2 18 ln2_g 19 ln2_b
// 20 lnf_g 21 lnf_b 22 Wlm 23 blm
// Output: logits [2,1024,32000] f32 then loss scalar at d_out[65536000].

constexpr int Lc = 4, Hc = 12, Ec = 768, HSc = 64, Vc = 32000, Bc = 2, Tc = 1024;
constexpr int BTc = Bc * Tc;               // 2048
constexpr int QKVW = 3 * Ec;               // 2304
constexpr size_t NLOGITS = (size_t)BTc * Vc;  // 65,536,000

// ---------------- repack QKV weights: [L][H][E][HS] -> [L][E][3*768] ----------------
__global__ void repack_wqkv(const float* __restrict__ Wq, const float* __restrict__ Wk,
                            const float* __restrict__ Wv, float* __restrict__ Wp) {
  int i = blockIdx.x * 256 + threadIdx.x;
  if (i >= Lc * Ec * QKVW) return;
  int col = i % QKVW;
  int e = (i / QKVW) % Ec;
  int l = i / (QKVW * Ec);
  const float* src;
  int c = col;
  if (c < Ec) { src = Wq; }
  else if (c < 2 * Ec) { src = Wk; c -= Ec; }
  else { src = Wv; c -= 2 * Ec; }
  int h = c >> 6, hs = c & 63;
  Wp[i] = src[(((size_t)l * Hc + h) * Ec + e) * HSc + hs];
}

__global__ void repack_bqkv(const float* __restrict__ bq, const float* __restrict__ bk,
                            const float* __restrict__ bv, float* __restrict__ bp) {
  int i = blockIdx.x * 256 + threadIdx.x;
  if (i >= Lc * QKVW) return;
  int col = i % QKVW;
  int l = i / QKVW;
  float v;
  if (col < Ec) v = bq[l * Ec + col];
  else if (col < 2 * Ec) v = bk[l * Ec + col - Ec];
  else v = bv[l * Ec + col - 2 * Ec];
  bp[i] = v;
}

// ---------------- embedding ----------------
__global__ void embed_kernel(const int* __restrict__ idx, const float* __restrict__ tok,
                             const float* __restrict__ pos, float* __restrict__ x) {
  int i = blockIdx.x * 256 + threadIdx.x;  // float4 index, total 2048*192
  if (i >= BTc * (Ec / 4)) return;
  int row = i / (Ec / 4);
  int e4 = i % (Ec / 4);
  int t = row & (Tc - 1);
  int token = idx[row];
  float4 a = ((const float4*)(tok + (size_t)token * Ec))[e4];
  float4 b = ((const float4*)(pos + (size_t)t * Ec))[e4];
  float4 o;
  o.x = a.x + b.x; o.y = a.y + b.y; o.z = a.z + b.z; o.w = a.w + b.w;
  ((float4*)(x + (size_t)row * Ec))[e4] = o;
}

// ---------------- layernorm (row = 768) ----------------
__global__ __launch_bounds__(256) void ln_kernel(const float* __restrict__ in,
                                                 const float* __restrict__ g,
                                                 const float* __restrict__ b,
                                                 float* __restrict__ out) {
  int row = blockIdx.x;
  int tid = threadIdx.x;
  const float* xr = in + (size_t)row * Ec;
  float v0 = xr[tid], v1 = xr[tid + 256], v2 = xr[tid + 512];
  float s = v0 + v1 + v2;
  float sq = v0 * v0 + v1 * v1 + v2 * v2;
  __shared__ float rs[256], rq[256];
  rs[tid] = s; rq[tid] = sq;
  __syncthreads();
  for (int off = 128; off > 0; off >>= 1) {
    if (tid < off) { rs[tid] += rs[tid + off]; rq[tid] += rq[tid + off]; }
    __syncthreads();
  }
  float mean = rs[0] * (1.f / Ec);
  float var = rq[0] * (1.f / Ec) - mean * mean;
  float rstd = rsqrtf(var + 1e-5f);
  float* orow = out + (size_t)row * Ec;
  orow[tid]       = (v0 - mean) * rstd * g[tid]       + b[tid];
  orow[tid + 256] = (v1 - mean) * rstd * g[tid + 256] + b[tid + 256];
  orow[tid + 512] = (v2 - mean) * rstd * g[tid + 512] + b[tid + 512];
}

// ---------------- f32 GEMM: C[M,N] = A[M,K] @ B[K,N] + bias (+res) (relu) ----------------
// MODE 0: bias; MODE 1: bias + relu; MODE 2: bias + residual
template <int MODE>
__global__ __launch_bounds__(256) void gemm_f32(const float* __restrict__ A,
                                                const float* __restrict__ B,
                                                const float* __restrict__ bias,
                                                const float* __restrict__ Res,
                                                float* __restrict__ C,
                                                int M, int N, int K) {
  __shared__ float As[16][132];  // transposed A tile: As[k][m]
  __shared__ float Bs[16][132];
  const int tid = threadIdx.x;
  const int n0 = blockIdx.x * 128;
  const int m0 = blockIdx.y * 128;
  const int tx = tid & 15, ty = tid >> 4;

  float acc[8][8];
#pragma unroll
  for (int i = 0; i < 8; i++)
#pragma unroll
    for (int j = 0; j < 8; j++) acc[i][j] = 0.f;

  for (int kt = 0; kt < K; kt += 16) {
#pragma unroll
    for (int it = 0; it < 2; it++) {
      int fidx = it * 256 + tid;
      int ar = fidx >> 2, aq = fidx & 3;
      float4 av = *(const float4*)(A + (size_t)(m0 + ar) * K + kt + aq * 4);
      As[aq * 4 + 0][ar] = av.x;
      As[aq * 4 + 1][ar] = av.y;
      As[aq * 4 + 2][ar] = av.z;
      As[aq * 4 + 3][ar] = av.w;
      int br = fidx >> 5, bq = fidx & 31;
      float4 bv = *(const float4*)(B + (size_t)(kt + br) * N + n0 + bq * 4);
      *(float4*)(&Bs[br][bq * 4]) = bv;
    }
    __syncthreads();
#pragma unroll
    for (int kk = 0; kk < 16; kk++) {
      float a[8], b[8];
      *(float4*)(a + 0) = *(const float4*)(&As[kk][ty * 8]);
      *(float4*)(a + 4) = *(const float4*)(&As[kk][ty * 8 + 4]);
      *(float4*)(b + 0) = *(const float4*)(&Bs[kk][tx * 4]);
      *(float4*)(b + 4) = *(const float4*)(&Bs[kk][64 + tx * 4]);
#pragma unroll
      for (int i = 0; i < 8; i++)
#pragma unroll
        for (int j = 0; j < 8; j++) acc[i][j] = fmaf(a[i], b[j], acc[i][j]);
    }
    __syncthreads();
  }

#pragma unroll
  for (int i = 0; i < 8; i++) {
    int gm = m0 + ty * 8 + i;
#pragma unroll
    for (int c = 0; c < 2; c++) {
      int gn = n0 + c * 64 + tx * 4;
      float4 bv = *(const float4*)(bias + gn);
      float r[4] = {acc[i][c * 4 + 0] + bv.x, acc[i][c * 4 + 1] + bv.y,
                    acc[i][c * 4 + 2] + bv.z, acc[i][c * 4 + 3] + bv.w};
      if (MODE == 2) {
        float4 rv = *(const float4*)(Res + (size_t)gm * N + gn);
        r[0] += rv.x; r[1] += rv.y; r[2] += rv.z; r[3] += rv.w;
      }
      if (MODE == 1) {
#pragma unroll
        for (int j = 0; j < 4; j++) r[j] = fmaxf(r[j], 0.f);
      }
      float4 o; o.x = r[0]; o.y = r[1]; o.z = r[2]; o.w = r[3];
      *(float4*)(C + (size_t)gm * N + gn) = o;
    }
  }
}

// ---------------- flash attention (f32), 4 lanes per query row ----------------
// qkv layout: [BT][2304], q at col h*64, k at 768+h*64, v at 1536+h*64
// out layout: [BT][768] (heads concatenated)
// Block: 256 threads = 64 query rows x 4 lanes. Each lane owns 16 of 64 dims.
// Dot product reduced across the 4-lane group with __shfl_xor; softmax state
// (m, l) is computed redundantly (identically) on all 4 lanes.
__global__ __launch_bounds__(256) void attn_flash(const float* __restrict__ qkv,
                                                  float* __restrict__ out) {
  __shared__ float Ks[64][68];  // stride 68 floats, coprime w/ 32 banks
  __shared__ float Vs[64][68];
  const int bh = blockIdx.x;                 // 0..23
  const int b = bh / Hc, h = bh % Hc;
  const int by = (int)gridDim.y - 1 - (int)blockIdx.y;  // heavy tiles dispatch first
  const int tid = threadIdx.x;               // 0..255
  const int r = tid >> 2;                    // query row within tile, 0..63
  const int c = tid & 3;                     // dim-quarter, 0..3
  const int qi = by * 64 + r;

  const float* qb = qkv + (size_t)(b * Tc + qi) * QKVW + h * 64 + c * 16;
  float q[16], o[16];
#pragma unroll
  for (int i = 0; i < 4; i++) {
    float4 v = ((const float4*)qb)[i];
    q[4 * i + 0] = v.x * 0.125f;
    q[4 * i + 1] = v.y * 0.125f;
    q[4 * i + 2] = v.z * 0.125f;
    q[4 * i + 3] = v.w * 0.125f;
  }
#pragma unroll
  for (int k = 0; k < 16; k++) o[k] = 0.f;
  float m = -1e30f, l = 0.f;

  for (int kt = 0; kt <= by; kt++) {
    __syncthreads();
    // cooperative K/V tile load: thread (r,c) loads row r, float4s [4c..4c+3]
    const float* kb = qkv + (size_t)(b * Tc + kt * 64 + r) * QKVW + h * 64 + Ec;
#pragma unroll
    for (int i = 0; i < 4; i++) {
      ((float4*)&Ks[r][0])[c * 4 + i] = ((const float4*)kb)[c * 4 + i];
      ((float4*)&Vs[r][0])[c * 4 + i] = ((const float4*)(kb + Ec))[c * 4 + i];
    }
    __syncthreads();
    const int jmax = (kt == by) ? (r + 1) : 64;
    for (int j = 0; j < jmax; j++) {
      const float4* kr4 = (const float4*)&Ks[j][c * 16];
      // 4 independent partial accumulators -> short dependency chain
      float s0 = 0.f, s1 = 0.f, s2 = 0.f, s3 = 0.f;
      {
        float4 kv0 = kr4[0], kv1 = kr4[1], kv2 = kr4[2], kv3 = kr4[3];
        s0 = fmaf(q[0], kv0.x, s0); s0 = fmaf(q[1], kv0.y, s0);
        s0 = fmaf(q[2], kv0.z, s0); s0 = fmaf(q[3], kv0.w, s0);
        s1 = fmaf(q[4], kv1.x, s1); s1 = fmaf(q[5], kv1.y, s1);
        s1 = fmaf(q[6], kv1.z, s1); s1 = fmaf(q[7], kv1.w, s1);
        s2 = fmaf(q[8], kv2.x, s2); s2 = fmaf(q[9], kv2.y, s2);
        s2 = fmaf(q[10], kv2.z, s2); s2 = fmaf(q[11], kv2.w, s2);
        s3 = fmaf(q[12], kv3.x, s3); s3 = fmaf(q[13], kv3.y, s3);
        s3 = fmaf(q[14], kv3.z, s3); s3 = fmaf(q[15], kv3.w, s3);
      }
      float s = (s0 + s1) + (s2 + s3);
      s += __shfl_xor(s, 1);
      s += __shfl_xor(s, 2);  // all 4 lanes now hold the full dot product
      float mn = fmaxf(m, s);
      float alpha = __expf(m - mn);
      float p = __expf(s - mn);
      l = l * alpha + p;
      const float4* vr4 = (const float4*)&Vs[j][c * 16];
#pragma unroll
      for (int k4 = 0; k4 < 4; k4++) {
        float4 vv = vr4[k4];
        o[4 * k4 + 0] = fmaf(o[4 * k4 + 0], alpha, p * vv.x);
        o[4 * k4 + 1] = fmaf(o[4 * k4 + 1], alpha, p * vv.y);
        o[4 * k4 + 2] = fmaf(o[4 * k4 + 2], alpha, p * vv.z);
        o[4 * k4 + 3] = fmaf(o[4 * k4 + 3], alpha, p * vv.w);
      }
      m = mn;
    }
  }
  float inv = 1.f / l;
  float* ob = out + (size_t)(b * Tc + qi) * Ec + h * 64 + c * 16;
#pragma unroll
  for (int i = 0; i < 4; i++) {
    float4 v;
    v.x = o[4 * i + 0] * inv;
    v.y = o[4 * i + 1] * inv;
    v.z = o[4 * i + 2] * inv;
    v.w = o[4 * i + 3] * inv;
    ((float4*)ob)[i] = v;
  }
}

// ---------------- loss ----------------
__global__ void zero_one(float* __restrict__ p) {
  if (blockIdx.x == 0 && threadIdx.x == 0) *p = 0.f;
}

__global__ __launch_bounds__(256) void loss_kernel(const float* __restrict__ logits,
                                                   const int* __restrict__ targets,
                                                   float* __restrict__ loss) {
  int row = blockIdx.x;
  int tid = threadIdx.x;
  const float* lg = logits + (size_t)row * Vc;
  float m = -1e30f;
  for (int v = tid; v < Vc; v += 256) m = fmaxf(m, lg[v]);
  __shared__ float red[256];
  red[tid] = m;
  __syncthreads();
  for (int off = 128; off > 0; off >>= 1) {
    if (tid < off) red[tid] = fmaxf(red[tid], red[tid + off]);
    __syncthreads();
  }
  m = red[0];
  __syncthreads();
  float s = 0.f;
  for (int v = tid; v < Vc; v += 256) s += __expf(lg[v] - m);
  red[tid] = s;
  __syncthreads();
  for (int off = 128; off > 0; off >>= 1) {
    if (tid < off) red[tid] += red[tid + off];
    __syncthreads();
  }
  if (tid == 0) {
    float lse = logf(red[0]) + m;
    float lt = lg[targets[row]];
    atomicAdd(loss, (lse - lt) * (1.0f / BTc));
  }
}

// ---------------- launch ----------------
extern "C" void kernel_launch(void* const* d_in, const int* in_sizes, int n_in,
                              void* d_out, int out_size, void* d_ws, size_t ws_size,
                              hipStream_t stream) {
  const int*   idx     = (const int*)d_in[0];
  const int*   targets = (const int*)d_in[1];
  const float* tok_emb = (const float*)d_in[2];
  const float* pos_emb = (const float*)d_in[3];
  const float* Wq = (const float*)d_in[4];
  const float* bq = (const float*)d_in[5];
  const float* Wk = (const float*)d_in[6];
  const float* bk = (const float*)d_in[7];
  const float* Wv = (const float*)d_in[8];
  const float* bv = (const float*)d_in[9];
  const float* Wo = (const float*)d_in[10];
  const float* bo = (const float*)d_in[11];
  const float* ln1_g = (const float*)d_in[12];
  const float* ln1_b = (const float*)d_in[13];
  const float* W1 = (const float*)d_in[14];
  const float* b1 = (const float*)d_in[15];
  const float* W2 = (const float*)d_in[16];
  const float* b2 = (const float*)d_in[17];
  const float* ln2_g = (const float*)d_in[18];
  const float* ln2_b = (const float*)d_in[19];
  const float* lnf_g = (const float*)d_in[20];
  const float* lnf_b = (const float*)d_in[21];
  const float* Wlm = (const float*)d_in[22];
  const float* blm = (const float*)d_in[23];
  float* out = (float*)d_out;

  float* ws = (float*)d_ws;
  float* x    = ws;                       // 2048*768   = 1,572,864
  float* tmp  = x + (size_t)BTc * Ec;     // 1,572,864
  float* qkv  = tmp + (size_t)BTc * Ec;   // 2048*2304  = 4,718,592
  float* mlph = qkv + (size_t)BTc * QKVW; // 2048*3072  = 6,291,456
  float* wp   = mlph + (size_t)BTc * 4 * Ec;  // 4*768*2304 = 7,077,888
  float* bp   = wp + (size_t)Lc * Ec * QKVW;  // 4*2304

  // repack QKV weights/biases
  repack_wqkv<<<(Lc * Ec * QKVW + 255) / 256, 256, 0, stream>>>(Wq, Wk, Wv, wp);
  repack_bqkv<<<(Lc * QKVW + 255) / 256, 256, 0, stream>>>(bq, bk, bv, bp);

  // embedding
  embed_kernel<<<(BTc * (Ec / 4) + 255) / 256, 256, 0, stream>>>(idx, tok_emb, pos_emb, x);

  for (int l = 0; l < Lc; l++) {
    ln_kernel<<<BTc, 256, 0, stream>>>(x, ln1_g + l * Ec, ln1_b + l * Ec, tmp);
    gemm_f32<0><<<dim3(QKVW / 128, BTc / 128), 256, 0, stream>>>(
        tmp, wp + (size_t)l * Ec * QKVW, bp + l * QKVW, nullptr, qkv, BTc, QKVW, Ec);
    attn_flash<<<dim3(Bc * Hc, Tc / 64), 256, 0, stream>>>(qkv, tmp);
    gemm_f32<2><<<dim3(Ec / 128, BTc / 128), 256, 0, stream>>>(
        tmp, Wo + (size_t)l * Ec * Ec, bo + l * Ec, x, x, BTc, Ec, Ec);
    ln_kernel<<<BTc, 256, 0, stream>>>(x, ln2_g + l * Ec, ln2_b + l * Ec, tmp);
    gemm_f32<1><<<dim3(4 * Ec / 128, BTc / 128), 256, 0, stream>>>(
        tmp, W1 + (size_t)l * Ec * 4 * Ec, b1 + l * 4 * Ec, nullptr, mlph, BTc, 4 * Ec, Ec);
    gemm_f32<2><<<dim3(Ec / 128, BTc / 128), 256, 0, stream>>>(
        mlph, W2 + (size_t)l * 4 * Ec * Ec, b2 + l * Ec, x, x, BTc, Ec, 4 * Ec);
  }

  // final LN + LM head -> logits into d_out
  ln_kernel<<<BTc, 256, 0, stream>>>(x, lnf_g, lnf_b, tmp);
  gemm_f32<0><<<dim3(Vc / 128, BTc / 128), 256, 0, stream>>>(
      tmp, Wlm, blm, nullptr, out, BTc, Vc, Ec);

  // loss
  zero_one<<<1, 64, 0, stream>>>(out + NLOGITS);
  loss_kernel<<<BTc, 256, 0, stream>>>(out, targets, out + NLOGITS);
}

// Round 3
// 2221.728 us; speedup vs baseline: 4.2330x; 2.5266x over previous
//
#include <hip/hip_runtime.h>
#include <math.h>

// GPT forward: L=4, H=12, E=768, HS=64, V=32000, B=2, T=1024
// Output: logits [2,1024,32000] f32 then loss scalar at d_out[65536000].
//
// Workspace budget (88.1 MB total — cap suspected 128 MB; 147 MB crashed):
//   actb  bf16  3,145,728
//   bp    f32      36,864
//   region (reusable, 84,934,656):
//     x f32 6,291,456 | qkvb bf16 9,437,184 | mlphb bf16 12,582,912
//     wqkvp 14,155,776 | wop 4,718,592 | w1p 18,874,368 | w2p 18,874,368
//   wlmp bf16 49,152,000 ALIASES region front (transposed only after layers,
//   when x/qkvb/mlphb/weight packs are all dead).

typedef unsigned short u16;
typedef short v8s __attribute__((ext_vector_type(8)));   // 8 bf16 (MFMA A/B frag)
typedef float v4f __attribute__((ext_vector_type(4)));   // MFMA accumulator

constexpr int Lc = 4, Hc = 12, Ec = 768, HSc = 64, Vc = 32000, Bc = 2, Tc = 1024;
constexpr int BTc = Bc * Tc;               // 2048
constexpr int QKVW = 3 * Ec;               // 2304
constexpr size_t NLOGITS = (size_t)BTc * Vc;

// round-to-nearest-even f32 -> bf16
__device__ inline u16 f2bf(float f) {
  unsigned u = __builtin_bit_cast(unsigned, f);
  u += 0x7fff + ((u >> 16) & 1);
  return (u16)(u >> 16);
}
__device__ inline float bf2f(u16 u) {
  return __builtin_bit_cast(float, (unsigned)u << 16);
}

__device__ inline void gload16(const void* g, void* l) {
  __builtin_amdgcn_global_load_lds(
      (const __attribute__((address_space(1))) void*)g,
      (__attribute__((address_space(3))) void*)l, 16, 0, 0);
}

// ---------------- weight repack: transpose + cast to bf16 [N][K] ----------------
// src f32 [R][C] row-major (batch via blockIdx.z, stride R*C) -> dst bf16 [C][R]
__global__ __launch_bounds__(256) void transpose_cast(const float* __restrict__ src,
                                                      u16* __restrict__ dst,
                                                      int R, int C) {
  __shared__ float t[32][33];
  const float* s = src + (size_t)blockIdx.z * R * C;
  u16* d = dst + (size_t)blockIdx.z * R * C;
  int c0 = blockIdx.x * 32, r0 = blockIdx.y * 32;
  int tx = threadIdx.x & 31, ty = threadIdx.x >> 5;  // ty 0..7
#pragma unroll
  for (int i = 0; i < 32; i += 8)
    t[ty + i][tx] = s[(size_t)(r0 + ty + i) * C + c0 + tx];
  __syncthreads();
#pragma unroll
  for (int i = 0; i < 32; i += 8)
    d[(size_t)(c0 + ty + i) * R + r0 + tx] = f2bf(t[tx][ty + i]);
}

// QKV: [L][H][E][HS] (x3) -> bf16 [L][N=2304][K=768], n = part*768 + h*64 + hs
__global__ __launch_bounds__(256) void repack_qkv_bf16(const float* __restrict__ Wq,
                                                       const float* __restrict__ Wk,
                                                       const float* __restrict__ Wv,
                                                       u16* __restrict__ dst) {
  __shared__ float t[32][33];
  int z = blockIdx.z;                       // l*36 + part*12 + h
  int l = z / 36, part = (z / 12) % 3, h = z % 12;
  const float* W = (part == 0) ? Wq : (part == 1) ? Wk : Wv;
  const float* s = W + ((size_t)l * Hc + h) * Ec * HSc;   // [768][64]
  int hs0 = blockIdx.x * 32, k0 = blockIdx.y * 32;
  int tx = threadIdx.x & 31, ty = threadIdx.x >> 5;
#pragma unroll
  for (int i = 0; i < 32; i += 8)
    t[ty + i][tx] = s[(size_t)(k0 + ty + i) * HSc + hs0 + tx];
  __syncthreads();
  u16* drow = dst + ((size_t)l * QKVW + part * Ec + h * 64) * Ec;
#pragma unroll
  for (int i = 0; i < 32; i += 8)
    drow[(size_t)(hs0 + ty + i) * Ec + k0 + tx] = f2bf(t[tx][ty + i]);
}

__global__ void repack_bqkv(const float* __restrict__ bq, const float* __restrict__ bk,
                            const float* __restrict__ bv, float* __restrict__ bp) {
  int i = blockIdx.x * 256 + threadIdx.x;
  if (i >= Lc * QKVW) return;
  int col = i % QKVW;
  int l = i / QKVW;
  float v;
  if (col < Ec) v = bq[l * Ec + col];
  else if (col < 2 * Ec) v = bk[l * Ec + col - Ec];
  else v = bv[l * Ec + col - 2 * Ec];
  bp[i] = v;
}

// ---------------- embedding ----------------
__global__ void embed_kernel(const int* __restrict__ idx, const float* __restrict__ tok,
                             const float* __restrict__ pos, float* __restrict__ x) {
  int i = blockIdx.x * 256 + threadIdx.x;
  if (i >= BTc * (Ec / 4)) return;
  int row = i / (Ec / 4);
  int e4 = i % (Ec / 4);
  int t = row & (Tc - 1);
  int token = idx[row];
  float4 a = ((const float4*)(tok + (size_t)token * Ec))[e4];
  float4 b = ((const float4*)(pos + (size_t)t * Ec))[e4];
  float4 o;
  o.x = a.x + b.x; o.y = a.y + b.y; o.z = a.z + b.z; o.w = a.w + b.w;
  ((float4*)(x + (size_t)row * Ec))[e4] = o;
}

// ---------------- layernorm (row = 768), f32 in -> bf16 out ----------------
__global__ __launch_bounds__(256) void ln_kernel(const float* __restrict__ in,
                                                 const float* __restrict__ g,
                                                 const float* __restrict__ b,
                                                 u16* __restrict__ out) {
  int row = blockIdx.x;
  int tid = threadIdx.x;
  const float* xr = in + (size_t)row * Ec;
  float v0 = xr[tid], v1 = xr[tid + 256], v2 = xr[tid + 512];
  float s = v0 + v1 + v2;
  float sq = v0 * v0 + v1 * v1 + v2 * v2;
  __shared__ float rs[256], rq[256];
  rs[tid] = s; rq[tid] = sq;
  __syncthreads();
  for (int off = 128; off > 0; off >>= 1) {
    if (tid < off) { rs[tid] += rs[tid + off]; rq[tid] += rq[tid + off]; }
    __syncthreads();
  }
  float mean = rs[0] * (1.f / Ec);
  float var = rq[0] * (1.f / Ec) - mean * mean;
  float rstd = rsqrtf(var + 1e-5f);
  u16* orow = out + (size_t)row * Ec;
  orow[tid]       = f2bf((v0 - mean) * rstd * g[tid]       + b[tid]);
  orow[tid + 256] = f2bf((v1 - mean) * rstd * g[tid + 256] + b[tid + 256]);
  orow[tid + 512] = f2bf((v2 - mean) * rstd * g[tid + 512] + b[tid + 512]);
}

// ---------------- bf16 MFMA GEMM: C[M,N] = A[M,K] @ Bt[N,K]^T ----------------
// A bf16 [M][K], Bt bf16 [N][K]. 128x128 tile, BK=32, 4 waves (2x2) of 64x64.
// LDS staged via global_load_lds w16 with source-side XOR swizzle q^=(row>>1)&3
// so fragment ds_read_b128 is ~2-way-conflict-free.
// MODE 0: bias -> f32; MODE 1: bias+relu -> bf16; MODE 2: bias+res -> f32;
// MODE 3: bias -> bf16.
template <int MODE>
__global__ __launch_bounds__(256) void gemm_bf16(const u16* __restrict__ A,
                                                 const u16* __restrict__ Bt,
                                                 const float* __restrict__ bias,
                                                 const float* __restrict__ Res,
                                                 void* __restrict__ Cout,
                                                 int M, int N, int K) {
  __shared__ __align__(128) char smem[16384];  // A tile 8KB | B tile 8KB
  const int tid = threadIdx.x;
  const int lane = tid & 63, wid = tid >> 6;
  const int wm = wid >> 1, wn = wid & 1;
  const int n0 = blockIdx.x * 128, m0 = blockIdx.y * 128;

  // staging: wave wid stages rows wid*16..+15 (ldsX0) and 64+wid*16..+15 (ldsX1).
  // physical slot (rowp, qp=lane&3); fetch logical chunk ql = qp ^ ((rowp>>1)&3).
  const int rowp0 = wid * 16 + (lane >> 2);
  const int qp = lane & 3;
  const int ql0 = qp ^ ((rowp0 >> 1) & 3);
  const int rowp1 = rowp0 + 64;
  const int ql1 = qp ^ ((rowp1 >> 1) & 3);
  char* ldsA0 = smem + wid * 1024;
  char* ldsA1 = smem + wid * 1024 + 4096;
  char* ldsB0 = smem + 8192 + wid * 1024;
  char* ldsB1 = smem + 8192 + wid * 1024 + 4096;
  const u16* Ag0 = A + (size_t)(m0 + rowp0) * K + ql0 * 8;
  const u16* Ag1 = A + (size_t)(m0 + rowp1) * K + ql1 * 8;
  const u16* Bg0 = Bt + (size_t)(n0 + rowp0) * K + ql0 * 8;
  const u16* Bg1 = Bt + (size_t)(n0 + rowp1) * K + ql1 * 8;

  // fragment reads: row = w*64 + f*16 + (lane&15), logical k-chunk = lane>>4.
  const int fr = lane & 15, kq = lane >> 4;
  const int rowA = wm * 64 + fr, rowB = wn * 64 + fr;
  const char* ardp = smem + rowA * 64 + (kq ^ ((rowA >> 1) & 3)) * 16;
  const char* brdp = smem + 8192 + rowB * 64 + (kq ^ ((rowB >> 1) & 3)) * 16;

  v4f acc[4][4];
#pragma unroll
  for (int i = 0; i < 4; i++)
#pragma unroll
    for (int j = 0; j < 4; j++) acc[i][j] = (v4f)0.f;

  for (int kt = 0; kt < K; kt += 32) {
    gload16(Ag0 + kt, ldsA0);
    gload16(Ag1 + kt, ldsA1);
    gload16(Bg0 + kt, ldsB0);
    gload16(Bg1 + kt, ldsB1);
    __syncthreads();  // compiler drains vmcnt before s_barrier
    v8s a[4], b[4];
#pragma unroll
    for (int i = 0; i < 4; i++) a[i] = *(const v8s*)(ardp + i * 1024);
#pragma unroll
    for (int i = 0; i < 4; i++) b[i] = *(const v8s*)(brdp + i * 1024);
#pragma unroll
    for (int m = 0; m < 4; m++)
#pragma unroll
      for (int n = 0; n < 4; n++)
        acc[m][n] = __builtin_amdgcn_mfma_f32_16x16x32_bf16(a[m], b[n], acc[m][n], 0, 0, 0);
    __syncthreads();
  }

  // epilogue: C row = m0+wm*64+fm*16+(lane>>4)*4+j, col = n0+wn*64+fn*16+(lane&15)
  const int cRow = m0 + wm * 64 + kq * 4;
  const int cCol = n0 + wn * 64 + fr;
#pragma unroll
  for (int fn = 0; fn < 4; fn++) {
    int col = cCol + fn * 16;
    float bv = bias[col];
#pragma unroll
    for (int fm = 0; fm < 4; fm++) {
#pragma unroll
      for (int j = 0; j < 4; j++) {
        int row = cRow + fm * 16 + j;
        float r = acc[fm][fn][j] + bv;
        if (MODE == 2) r += Res[(size_t)row * N + col];
        if (MODE == 1) r = fmaxf(r, 0.f);
        if (MODE == 1 || MODE == 3) {
          ((u16*)Cout)[(size_t)row * N + col] = f2bf(r);
        } else {
          ((float*)Cout)[(size_t)row * N + col] = r;
        }
      }
    }
  }
}

// ---------------- flash attention (f32 math), 4 lanes per query row ----------------
// qkv bf16 [BT][2304] (q at h*64, k at 768+h*64, v at 1536+h*64); out bf16 [BT][768]
__global__ __launch_bounds__(256) void attn_flash(const u16* __restrict__ qkv,
                                                  u16* __restrict__ out) {
  __shared__ float Ks[64][68];
  __shared__ float Vs[64][68];
  const int bh = blockIdx.x;
  const int b = bh / Hc, h = bh % Hc;
  const int by = (int)gridDim.y - 1 - (int)blockIdx.y;
  const int tid = threadIdx.x;
  const int r = tid >> 2;
  const int c = tid & 3;
  const int qi = by * 64 + r;

  const u16* qb = qkv + (size_t)(b * Tc + qi) * QKVW + h * 64 + c * 16;
  float q[16], o[16];
#pragma unroll
  for (int i = 0; i < 4; i++) {
    short4 s4 = ((const short4*)qb)[i];
    q[4 * i + 0] = bf2f((u16)s4.x) * 0.125f;
    q[4 * i + 1] = bf2f((u16)s4.y) * 0.125f;
    q[4 * i + 2] = bf2f((u16)s4.z) * 0.125f;
    q[4 * i + 3] = bf2f((u16)s4.w) * 0.125f;
  }
#pragma unroll
  for (int k = 0; k < 16; k++) o[k] = 0.f;
  float m = -1e30f, l = 0.f;

  for (int kt = 0; kt <= by; kt++) {
    __syncthreads();
    // cooperative K/V tile load: thread (r,c) stages row r, elems c*16..c*16+15
    const u16* kb = qkv + (size_t)(b * Tc + kt * 64 + r) * QKVW + h * 64 + Ec;
#pragma unroll
    for (int i = 0; i < 4; i++) {
      short4 ks = ((const short4*)kb)[c * 4 + i];
      short4 vs = ((const short4*)(kb + Ec))[c * 4 + i];
      float4 kf, vf;
      kf.x = bf2f((u16)ks.x); kf.y = bf2f((u16)ks.y);
      kf.z = bf2f((u16)ks.z); kf.w = bf2f((u16)ks.w);
      vf.x = bf2f((u16)vs.x); vf.y = bf2f((u16)vs.y);
      vf.z = bf2f((u16)vs.z); vf.w = bf2f((u16)vs.w);
      ((float4*)&Ks[r][0])[c * 4 + i] = kf;
      ((float4*)&Vs[r][0])[c * 4 + i] = vf;
    }
    __syncthreads();
    const int jmax = (kt == by) ? (r + 1) : 64;
    for (int j = 0; j < jmax; j++) {
      const float4* kr4 = (const float4*)&Ks[j][c * 16];
      float s0 = 0.f, s1 = 0.f, s2 = 0.f, s3 = 0.f;
      {
        float4 kv0 = kr4[0], kv1 = kr4[1], kv2 = kr4[2], kv3 = kr4[3];
        s0 = fmaf(q[0], kv0.x, s0); s0 = fmaf(q[1], kv0.y, s0);
        s0 = fmaf(q[2], kv0.z, s0); s0 = fmaf(q[3], kv0.w, s0);
        s1 = fmaf(q[4], kv1.x, s1); s1 = fmaf(q[5], kv1.y, s1);
        s1 = fmaf(q[6], kv1.z, s1); s1 = fmaf(q[7], kv1.w, s1);
        s2 = fmaf(q[8], kv2.x, s2); s2 = fmaf(q[9], kv2.y, s2);
        s2 = fmaf(q[10], kv2.z, s2); s2 = fmaf(q[11], kv2.w, s2);
        s3 = fmaf(q[12], kv3.x, s3); s3 = fmaf(q[13], kv3.y, s3);
        s3 = fmaf(q[14], kv3.z, s3); s3 = fmaf(q[15], kv3.w, s3);
      }
      float s = (s0 + s1) + (s2 + s3);
      s += __shfl_xor(s, 1);
      s += __shfl_xor(s, 2);
      float mn = fmaxf(m, s);
      float alpha = __expf(m - mn);
      float p = __expf(s - mn);
      l = l * alpha + p;
      const float4* vr4 = (const float4*)&Vs[j][c * 16];
#pragma unroll
      for (int k4 = 0; k4 < 4; k4++) {
        float4 vv = vr4[k4];
        o[4 * k4 + 0] = fmaf(o[4 * k4 + 0], alpha, p * vv.x);
        o[4 * k4 + 1] = fmaf(o[4 * k4 + 1], alpha, p * vv.y);
        o[4 * k4 + 2] = fmaf(o[4 * k4 + 2], alpha, p * vv.z);
        o[4 * k4 + 3] = fmaf(o[4 * k4 + 3], alpha, p * vv.w);
      }
      m = mn;
    }
  }
  float inv = 1.f / l;
  u16* ob = out + (size_t)(b * Tc + qi) * Ec + h * 64 + c * 16;
  u16 t16[16];
#pragma unroll
  for (int i = 0; i < 16; i++) t16[i] = f2bf(o[i] * inv);
  *(v8s*)ob = *(const v8s*)t16;
  *(v8s*)(ob + 8) = *(const v8s*)(t16 + 8);
}

// ---------------- loss ----------------
__global__ void zero_one(float* __restrict__ p) {
  if (blockIdx.x == 0 && threadIdx.x == 0) *p = 0.f;
}

__global__ __launch_bounds__(256) void loss_kernel(const float* __restrict__ logits,
                                                   const int* __restrict__ targets,
                                                   float* __restrict__ loss) {
  int row = blockIdx.x;
  int tid = threadIdx.x;
  const float* lg = logits + (size_t)row * Vc;
  float m = -1e30f;
  for (int v = tid; v < Vc; v += 256) m = fmaxf(m, lg[v]);
  __shared__ float red[256];
  red[tid] = m;
  __syncthreads();
  for (int off = 128; off > 0; off >>= 1) {
    if (tid < off) red[tid] = fmaxf(red[tid], red[tid + off]);
    __syncthreads();
  }
  m = red[0];
  __syncthreads();
  float s = 0.f;
  for (int v = tid; v < Vc; v += 256) s += __expf(lg[v] - m);
  red[tid] = s;
  __syncthreads();
  for (int off = 128; off > 0; off >>= 1) {
    if (tid < off) red[tid] += red[tid + off];
    __syncthreads();
  }
  if (tid == 0) {
    float lse = logf(red[0]) + m;
    float lt = lg[targets[row]];
    atomicAdd(loss, (lse - lt) * (1.0f / BTc));
  }
}

// ---------------- launch ----------------
extern "C" void kernel_launch(void* const* d_in, const int* in_sizes, int n_in,
                              void* d_out, int out_size, void* d_ws, size_t ws_size,
                              hipStream_t stream) {
  const int*   idx     = (const int*)d_in[0];
  const int*   targets = (const int*)d_in[1];
  const float* tok_emb = (const float*)d_in[2];
  const float* pos_emb = (const float*)d_in[3];
  const float* Wq = (const float*)d_in[4];
  const float* bq = (const float*)d_in[5];
  const float* Wk = (const float*)d_in[6];
  const float* bk = (const float*)d_in[7];
  const float* Wv = (const float*)d_in[8];
  const float* bv = (const float*)d_in[9];
  const float* Wo = (const float*)d_in[10];
  const float* bo = (const float*)d_in[11];
  const float* ln1_g = (const float*)d_in[12];
  const float* ln1_b = (const float*)d_in[13];
  const float* W1 = (const float*)d_in[14];
  const float* b1 = (const float*)d_in[15];
  const float* W2 = (const float*)d_in[16];
  const float* b2 = (const float*)d_in[17];
  const float* ln2_g = (const float*)d_in[18];
  const float* ln2_b = (const float*)d_in[19];
  const float* lnf_g = (const float*)d_in[20];
  const float* lnf_b = (const float*)d_in[21];
  const float* Wlm = (const float*)d_in[22];
  const float* blm = (const float*)d_in[23];
  float* out = (float*)d_out;

  // ---- workspace layout (88.1 MB) ----
  char* p = (char*)d_ws;
  u16* actb = (u16*)p;  p += (size_t)BTc * Ec * 2;        //  3,145,728
  float* bp = (float*)p; p += (size_t)Lc * QKVW * 4;      //     36,864
  char* region = p;                                       // 84,934,656 reusable
  float* x    = (float*)(region);                         //  6,291,456
  u16* qkvb   = (u16*)(region + 6291456);                 //  9,437,184
  u16* mlphb  = (u16*)(region + 15728640);                // 12,582,912
  u16* wqkvp  = (u16*)(region + 28311552);                // 14,155,776
  u16* wop    = (u16*)(region + 42467328);                //  4,718,592
  u16* w1p    = (u16*)(region + 47185920);                // 18,874,368
  u16* w2p    = (u16*)(region + 66060288);                // 18,874,368 (end 84,934,656)
  u16* wlmp   = (u16*)(region);                           // 49,152,000 ALIAS (used after layers)

  // weight repack (bf16, transposed to [N][K]) — all except Wlm (deferred)
  repack_qkv_bf16<<<dim3(2, 24, Lc * 3 * Hc), 256, 0, stream>>>(Wq, Wk, Wv, wqkvp);
  repack_bqkv<<<(Lc * QKVW + 255) / 256, 256, 0, stream>>>(bq, bk, bv, bp);
  transpose_cast<<<dim3(Ec / 32, Ec / 32, Lc), 256, 0, stream>>>(Wo, wop, Ec, Ec);
  transpose_cast<<<dim3(4 * Ec / 32, Ec / 32, Lc), 256, 0, stream>>>(W1, w1p, Ec, 4 * Ec);
  transpose_cast<<<dim3(Ec / 32, 4 * Ec / 32, Lc), 256, 0, stream>>>(W2, w2p, 4 * Ec, Ec);

  // embedding
  embed_kernel<<<(BTc * (Ec / 4) + 255) / 256, 256, 0, stream>>>(idx, tok_emb, pos_emb, x);

  for (int l = 0; l < Lc; l++) {
    ln_kernel<<<BTc, 256, 0, stream>>>(x, ln1_g + l * Ec, ln1_b + l * Ec, actb);
    gemm_bf16<3><<<dim3(QKVW / 128, BTc / 128), 256, 0, stream>>>(
        actb, wqkvp + (size_t)l * Ec * QKVW, bp + l * QKVW, nullptr, qkvb, BTc, QKVW, Ec);
    attn_flash<<<dim3(Bc * Hc, Tc / 64), 256, 0, stream>>>(qkvb, actb);
    gemm_bf16<2><<<dim3(Ec / 128, BTc / 128), 256, 0, stream>>>(
        actb, wop + (size_t)l * Ec * Ec, bo + l * Ec, x, x, BTc, Ec, Ec);
    ln_kernel<<<BTc, 256, 0, stream>>>(x, ln2_g + l * Ec, ln2_b + l * Ec, actb);
    gemm_bf16<1><<<dim3(4 * Ec / 128, BTc / 128), 256, 0, stream>>>(
        actb, w1p + (size_t)l * Ec * 4 * Ec, b1 + l * 4 * Ec, nullptr, mlphb, BTc, 4 * Ec, Ec);
    gemm_bf16<2><<<dim3(Ec / 128, BTc / 128), 256, 0, stream>>>(
        mlphb, w2p + (size_t)l * 4 * Ec * Ec, b2 + l * Ec, x, x, BTc, Ec, 4 * Ec);
  }

  // final LN (consumes x) -> then Wlm repack may overwrite region
  ln_kernel<<<BTc, 256, 0, stream>>>(x, lnf_g, lnf_b, actb);
  transpose_cast<<<dim3(Vc / 32, Ec / 32, 1), 256, 0, stream>>>(Wlm, wlmp, Ec, Vc);
  gemm_bf16<0><<<dim3(Vc / 128, BTc / 128), 256, 0, stream>>>(
      actb, wlmp, blm, nullptr, out, BTc, Vc, Ec);

  // loss
  zero_one<<<1, 64, 0, stream>>>(out + NLOGITS);
  loss_kernel<<<BTc, 256, 0, stream>>>(out, targets, out + NLOGITS);
}

// Round 4
// 1532.334 us; speedup vs baseline: 6.1375x; 1.4499x over previous
//
#include <hip/hip_runtime.h>
#include <math.h>

// GPT forward: L=4, H=12, E=768, HS=64, V=32000, B=2, T=1024
// Output: logits [2,1024,32000] f32 then loss scalar at d_out[65536000].
//
// Workspace (91.3 MB): actb 3.1M | bp 37K | vt 3.1M | region 84.9M
//   region: x f32 | qkvb bf16 | mlphb bf16 | wqkvp | wop | w1p | w2p
//   wlmp (49.2M) ALIASES region front (built only after layers finish).

typedef unsigned short u16;
typedef short v8s __attribute__((ext_vector_type(8)));   // 8 bf16 (MFMA A/B frag)
typedef float v4f __attribute__((ext_vector_type(4)));   // MFMA accumulator

constexpr int Lc = 4, Hc = 12, Ec = 768, HSc = 64, Vc = 32000, Bc = 2, Tc = 1024;
constexpr int BTc = Bc * Tc;               // 2048
constexpr int QKVW = 3 * Ec;               // 2304
constexpr size_t NLOGITS = (size_t)BTc * Vc;

__device__ inline u16 f2bf(float f) {
  unsigned u = __builtin_bit_cast(unsigned, f);
  u += 0x7fff + ((u >> 16) & 1);
  return (u16)(u >> 16);
}
__device__ inline float bf2f(u16 u) {
  return __builtin_bit_cast(float, (unsigned)u << 16);
}

__device__ inline void gload16(const void* g, void* l) {
  __builtin_amdgcn_global_load_lds(
      (const __attribute__((address_space(1))) void*)g,
      (__attribute__((address_space(3))) void*)l, 16, 0, 0);
}

#define MFMA16(a, b, c) __builtin_amdgcn_mfma_f32_16x16x32_bf16((a), (b), (c), 0, 0, 0)

// ---------------- weight repack: transpose + cast to bf16 [N][K] ----------------
__global__ __launch_bounds__(256) void transpose_cast(const float* __restrict__ src,
                                                      u16* __restrict__ dst,
                                                      int R, int C) {
  __shared__ float t[32][33];
  const float* s = src + (size_t)blockIdx.z * R * C;
  u16* d = dst + (size_t)blockIdx.z * R * C;
  int c0 = blockIdx.x * 32, r0 = blockIdx.y * 32;
  int tx = threadIdx.x & 31, ty = threadIdx.x >> 5;  // ty 0..7
#pragma unroll
  for (int i = 0; i < 32; i += 8)
    t[ty + i][tx] = s[(size_t)(r0 + ty + i) * C + c0 + tx];
  __syncthreads();
#pragma unroll
  for (int i = 0; i < 32; i += 8)
    d[(size_t)(c0 + ty + i) * R + r0 + tx] = f2bf(t[tx][ty + i]);
}

// QKV: [L][H][E][HS] (x3) -> bf16 [L][N=2304][K=768], n = part*768 + h*64 + hs
__global__ __launch_bounds__(256) void repack_qkv_bf16(const float* __restrict__ Wq,
                                                       const float* __restrict__ Wk,
                                                       const float* __restrict__ Wv,
                                                       u16* __restrict__ dst) {
  __shared__ float t[32][33];
  int z = blockIdx.z;                       // l*36 + part*12 + h
  int l = z / 36, part = (z / 12) % 3, h = z % 12;
  const float* W = (part == 0) ? Wq : (part == 1) ? Wk : Wv;
  const float* s = W + ((size_t)l * Hc + h) * Ec * HSc;   // [768][64]
  int hs0 = blockIdx.x * 32, k0 = blockIdx.y * 32;
  int tx = threadIdx.x & 31, ty = threadIdx.x >> 5;
#pragma unroll
  for (int i = 0; i < 32; i += 8)
    t[ty + i][tx] = s[(size_t)(k0 + ty + i) * HSc + hs0 + tx];
  __syncthreads();
  u16* drow = dst + ((size_t)l * QKVW + part * Ec + h * 64) * Ec;
#pragma unroll
  for (int i = 0; i < 32; i += 8)
    drow[(size_t)(hs0 + ty + i) * Ec + k0 + tx] = f2bf(t[tx][ty + i]);
}

__global__ void repack_bqkv(const float* __restrict__ bq, const float* __restrict__ bk,
                            const float* __restrict__ bv, float* __restrict__ bp) {
  int i = blockIdx.x * 256 + threadIdx.x;
  if (i >= Lc * QKVW) return;
  int col = i % QKVW;
  int l = i / QKVW;
  float v;
  if (col < Ec) v = bq[l * Ec + col];
  else if (col < 2 * Ec) v = bk[l * Ec + col - Ec];
  else v = bv[l * Ec + col - 2 * Ec];
  bp[i] = v;
}

// ---------------- per-layer V transpose: qkvb V-part -> vt[bh][d][t] bf16 ----------------
__global__ __launch_bounds__(256) void vtrans(const u16* __restrict__ qkvb,
                                              u16* __restrict__ vt) {
  __shared__ u16 tile[64][72];
  const int t0 = blockIdx.x * 64;
  const int bh = blockIdx.y;
  const int b = bh / Hc, h = bh % Hc;
  const int tid = threadIdx.x;
  // stage 64 tokens x 64 dims (bf16)
#pragma unroll
  for (int r = 0; r < 2; r++) {
    int idx = r * 256 + tid;
    int t = idx >> 3, dc = idx & 7;
    *(v8s*)&tile[t][dc * 8] =
        *(const v8s*)(qkvb + (size_t)(b * Tc + t0 + t) * QKVW + 2 * Ec + h * 64 + dc * 8);
  }
  __syncthreads();
  // write vt[bh][d][t0..t0+63]
#pragma unroll
  for (int r = 0; r < 4; r++) {
    int idx = r * 256 + tid;
    int d = idx >> 4, tc = idx & 15;
    unsigned lo = (unsigned)tile[tc * 4 + 0][d] | ((unsigned)tile[tc * 4 + 1][d] << 16);
    unsigned hi = (unsigned)tile[tc * 4 + 2][d] | ((unsigned)tile[tc * 4 + 3][d] << 16);
    uint2 w; w.x = lo; w.y = hi;
    *(uint2*)(vt + (size_t)bh * HSc * Tc + (size_t)d * Tc + t0 + tc * 4) = w;
  }
}

// ---------------- embedding ----------------
__global__ void embed_kernel(const int* __restrict__ idx, const float* __restrict__ tok,
                             const float* __restrict__ pos, float* __restrict__ x) {
  int i = blockIdx.x * 256 + threadIdx.x;
  if (i >= BTc * (Ec / 4)) return;
  int row = i / (Ec / 4);
  int e4 = i % (Ec / 4);
  int t = row & (Tc - 1);
  int token = idx[row];
  float4 a = ((const float4*)(tok + (size_t)token * Ec))[e4];
  float4 b = ((const float4*)(pos + (size_t)t * Ec))[e4];
  float4 o;
  o.x = a.x + b.x; o.y = a.y + b.y; o.z = a.z + b.z; o.w = a.w + b.w;
  ((float4*)(x + (size_t)row * Ec))[e4] = o;
}

// ---------------- layernorm (row = 768), f32 in -> bf16 out ----------------
__global__ __launch_bounds__(256) void ln_kernel(const float* __restrict__ in,
                                                 const float* __restrict__ g,
                                                 const float* __restrict__ b,
                                                 u16* __restrict__ out) {
  int row = blockIdx.x;
  int tid = threadIdx.x;
  const float* xr = in + (size_t)row * Ec;
  float v0 = xr[tid], v1 = xr[tid + 256], v2 = xr[tid + 512];
  float s = v0 + v1 + v2;
  float sq = v0 * v0 + v1 * v1 + v2 * v2;
  __shared__ float rs[256], rq[256];
  rs[tid] = s; rq[tid] = sq;
  __syncthreads();
  for (int off = 128; off > 0; off >>= 1) {
    if (tid < off) { rs[tid] += rs[tid + off]; rq[tid] += rq[tid + off]; }
    __syncthreads();
  }
  float mean = rs[0] * (1.f / Ec);
  float var = rq[0] * (1.f / Ec) - mean * mean;
  float rstd = rsqrtf(var + 1e-5f);
  u16* orow = out + (size_t)row * Ec;
  orow[tid]       = f2bf((v0 - mean) * rstd * g[tid]       + b[tid]);
  orow[tid + 256] = f2bf((v1 - mean) * rstd * g[tid + 256] + b[tid + 256]);
  orow[tid + 512] = f2bf((v2 - mean) * rstd * g[tid + 512] + b[tid + 512]);
}

// ---------------- bf16 MFMA GEMM: C[M,N] = A[M,K] @ Bt[N,K]^T ----------------
// MODE 0: bias -> f32; MODE 1: bias+relu -> bf16; MODE 2: bias+res -> f32;
// MODE 3: bias -> bf16.
template <int MODE>
__global__ __launch_bounds__(256) void gemm_bf16(const u16* __restrict__ A,
                                                 const u16* __restrict__ Bt,
                                                 const float* __restrict__ bias,
                                                 const float* __restrict__ Res,
                                                 void* __restrict__ Cout,
                                                 int M, int N, int K) {
  __shared__ __align__(128) char smem[16384];  // A tile 8KB | B tile 8KB
  const int tid = threadIdx.x;
  const int lane = tid & 63, wid = tid >> 6;
  const int wm = wid >> 1, wn = wid & 1;
  const int n0 = blockIdx.x * 128, m0 = blockIdx.y * 128;

  const int rowp0 = wid * 16 + (lane >> 2);
  const int qp = lane & 3;
  const int ql0 = qp ^ ((rowp0 >> 1) & 3);
  const int rowp1 = rowp0 + 64;
  const int ql1 = qp ^ ((rowp1 >> 1) & 3);
  char* ldsA0 = smem + wid * 1024;
  char* ldsA1 = smem + wid * 1024 + 4096;
  char* ldsB0 = smem + 8192 + wid * 1024;
  char* ldsB1 = smem + 8192 + wid * 1024 + 4096;
  const u16* Ag0 = A + (size_t)(m0 + rowp0) * K + ql0 * 8;
  const u16* Ag1 = A + (size_t)(m0 + rowp1) * K + ql1 * 8;
  const u16* Bg0 = Bt + (size_t)(n0 + rowp0) * K + ql0 * 8;
  const u16* Bg1 = Bt + (size_t)(n0 + rowp1) * K + ql1 * 8;

  const int fr = lane & 15, kq = lane >> 4;
  const int rowA = wm * 64 + fr, rowB = wn * 64 + fr;
  const char* ardp = smem + rowA * 64 + (kq ^ ((rowA >> 1) & 3)) * 16;
  const char* brdp = smem + 8192 + rowB * 64 + (kq ^ ((rowB >> 1) & 3)) * 16;

  v4f acc[4][4];
#pragma unroll
  for (int i = 0; i < 4; i++)
#pragma unroll
    for (int j = 0; j < 4; j++) acc[i][j] = (v4f)0.f;

  for (int kt = 0; kt < K; kt += 32) {
    gload16(Ag0 + kt, ldsA0);
    gload16(Ag1 + kt, ldsA1);
    gload16(Bg0 + kt, ldsB0);
    gload16(Bg1 + kt, ldsB1);
    __syncthreads();
    v8s a[4], b[4];
#pragma unroll
    for (int i = 0; i < 4; i++) a[i] = *(const v8s*)(ardp + i * 1024);
#pragma unroll
    for (int i = 0; i < 4; i++) b[i] = *(const v8s*)(brdp + i * 1024);
#pragma unroll
    for (int m = 0; m < 4; m++)
#pragma unroll
      for (int n = 0; n < 4; n++)
        acc[m][n] = MFMA16(a[m], b[n], acc[m][n]);
    __syncthreads();
  }

  const int cRow = m0 + wm * 64 + kq * 4;
  const int cCol = n0 + wn * 64 + fr;
#pragma unroll
  for (int fn = 0; fn < 4; fn++) {
    int col = cCol + fn * 16;
    float bv = bias[col];
#pragma unroll
    for (int fm = 0; fm < 4; fm++) {
#pragma unroll
      for (int j = 0; j < 4; j++) {
        int row = cRow + fm * 16 + j;
        float r = acc[fm][fn][j] + bv;
        if (MODE == 2) r += Res[(size_t)row * N + col];
        if (MODE == 1) r = fmaxf(r, 0.f);
        if (MODE == 1 || MODE == 3) {
          ((u16*)Cout)[(size_t)row * N + col] = f2bf(r);
        } else {
          ((float*)Cout)[(size_t)row * N + col] = r;
        }
      }
    }
  }
}

// ---------------- MFMA flash attention ----------------
// Block = 256 thr = 4 waves; wave w owns 16 queries q0 = by*64 + w*16.
// Per 32-key tile: S^T[32k][16q] = K·Q^T (2 sub-tiles x 2 k-chunks, operands
// straight from global/L2 — K/V are 128KB per (b,h), L2-resident, no staging).
// Softmax per q-column is lane-local (2 shfl for max). P -> wave-private LDS
// [16][40] bf16 (pad 40 -> conflict-free b64 writes / b128 reads, no barriers).
// PV: O[16q][64d] += P·V with V frags from vt[bh][d][t] (16B contiguous).
// acc rescale crosses the q-layout change (col->row) via 4 shfls.
__global__ __launch_bounds__(256) void attn_mfma(const u16* __restrict__ qkv,
                                                 const u16* __restrict__ vt,
                                                 u16* __restrict__ out) {
  __shared__ u16 P_all[4][16][40];
  const int bh = blockIdx.x;
  const int b = bh / Hc, h = bh % Hc;
  const int by = (int)gridDim.y - 1 - (int)blockIdx.y;  // heavy tiles first
  const int tid = threadIdx.x;
  const int w = tid >> 6, l = tid & 63;
  const int lr = l & 15, lg = l >> 4;
  const int q0 = by * 64 + w * 16;
  u16 (*P_lds)[40] = P_all[w];

  // Q^T B-frags (held for the whole kernel): Q[q0+lr][c*32 + lg*8 ..+7]
  const u16* qrow = qkv + (size_t)(b * Tc + q0 + lr) * QKVW + h * 64;
  const v8s qf0 = *(const v8s*)(qrow + lg * 8);
  const v8s qf1 = *(const v8s*)(qrow + 32 + lg * 8);

  const u16* kp0 = qkv + (size_t)(b * Tc + lr) * QKVW + Ec + h * 64 + lg * 8;
  const u16* vbase = vt + (size_t)bh * HSc * Tc;

  v4f acc[4];
#pragma unroll
  for (int dt = 0; dt < 4; dt++) acc[dt] = (v4f)0.f;
  float m = -1e30f, lsum = 0.f;
  const float SC = 0.125f;  // 1/sqrt(64)

  const int ntiles = (q0 + 47) >> 5;
  const int nfull = (q0 >= 31) ? ((q0 - 31) >> 5) + 1 : 0;

  for (int kt = 0; kt < ntiles; kt++) {
    const int k0 = kt * 32;
    // K A-frags: rows = keys k0 + sub*16 + lr, k-dims lg*8 (+32 for chunk 1)
    const u16* ka = kp0 + (size_t)k0 * QKVW;
    const u16* kb = ka + (size_t)16 * QKVW;
    v8s a00 = *(const v8s*)ka;
    v8s a01 = *(const v8s*)(ka + 32);
    v8s a10 = *(const v8s*)kb;
    v8s a11 = *(const v8s*)(kb + 32);
    v4f s0 = (v4f)0.f, s1 = (v4f)0.f;
    s0 = MFMA16(a00, qf0, s0);
    s0 = MFMA16(a01, qf1, s0);
    s1 = MFMA16(a10, qf0, s1);
    s1 = MFMA16(a11, qf1, s1);
    // causal mask: key (row = k0 + sub*16 + lg*4 + j) vs query (col = q0 + lr)
    if (kt >= nfull) {
      const int qg = q0 + lr;
#pragma unroll
      for (int j = 0; j < 4; j++) {
        if (k0 + lg * 4 + j > qg) s0[j] = -1e30f;
        if (k0 + 16 + lg * 4 + j > qg) s1[j] = -1e30f;
      }
    }
    // column max: in-lane over 8, then across the 4 lane-groups
    float mx = fmaxf(fmaxf(fmaxf(s0[0], s0[1]), fmaxf(s0[2], s0[3])),
                     fmaxf(fmaxf(s1[0], s1[1]), fmaxf(s1[2], s1[3])));
    mx = fmaxf(mx, __shfl_xor(mx, 16));
    mx = fmaxf(mx, __shfl_xor(mx, 32));
    const float mn = fmaxf(m, mx);
    const float alpha = __expf((m - mn) * SC);
    float p[8];
#pragma unroll
    for (int j = 0; j < 4; j++) {
      p[j] = __expf((s0[j] - mn) * SC);
      p[4 + j] = __expf((s1[j] - mn) * SC);
    }
    lsum = lsum * alpha + (((p[0] + p[1]) + (p[2] + p[3])) +
                           ((p[4] + p[5]) + (p[6] + p[7])));
    m = mn;
    // pack P^T -> P_lds[q][key-in-tile]
    uint2 w0, w1;
    w0.x = (unsigned)f2bf(p[0]) | ((unsigned)f2bf(p[1]) << 16);
    w0.y = (unsigned)f2bf(p[2]) | ((unsigned)f2bf(p[3]) << 16);
    w1.x = (unsigned)f2bf(p[4]) | ((unsigned)f2bf(p[5]) << 16);
    w1.y = (unsigned)f2bf(p[6]) | ((unsigned)f2bf(p[7]) << 16);
    *(uint2*)&P_lds[lr][lg * 4] = w0;
    *(uint2*)&P_lds[lr][16 + lg * 4] = w1;
    // alpha for acc rows (q = lg*4 + j lives in lane lg*4+j of S-phase layout)
    const float al0 = __shfl(alpha, lg * 4 + 0);
    const float al1 = __shfl(alpha, lg * 4 + 1);
    const float al2 = __shfl(alpha, lg * 4 + 2);
    const float al3 = __shfl(alpha, lg * 4 + 3);
    // P A-frag (same wave wrote it; lgkmcnt ordering suffices, no barrier)
    const v8s pa = *(const v8s*)&P_lds[lr][lg * 8];
#pragma unroll
    for (int dt = 0; dt < 4; dt++) {
      v4f t = acc[dt];
      t[0] *= al0; t[1] *= al1; t[2] *= al2; t[3] *= al3;
      const v8s bv = *(const v8s*)(vbase + (size_t)(dt * 16 + lr) * Tc + k0 + lg * 8);
      acc[dt] = MFMA16(pa, bv, t);
    }
  }
  // finalize: 1/l per q-column, broadcast to row layout
  lsum += __shfl_xor(lsum, 16);
  lsum += __shfl_xor(lsum, 32);
  const float inv = 1.f / lsum;
  const float i0 = __shfl(inv, lg * 4 + 0);
  const float i1 = __shfl(inv, lg * 4 + 1);
  const float i2 = __shfl(inv, lg * 4 + 2);
  const float i3 = __shfl(inv, lg * 4 + 3);
  u16* ob = out + (size_t)(b * Tc + q0) * Ec + h * 64;
#pragma unroll
  for (int dt = 0; dt < 4; dt++) {
    ob[(size_t)(lg * 4 + 0) * Ec + dt * 16 + lr] = f2bf(acc[dt][0] * i0);
    ob[(size_t)(lg * 4 + 1) * Ec + dt * 16 + lr] = f2bf(acc[dt][1] * i1);
    ob[(size_t)(lg * 4 + 2) * Ec + dt * 16 + lr] = f2bf(acc[dt][2] * i2);
    ob[(size_t)(lg * 4 + 3) * Ec + dt * 16 + lr] = f2bf(acc[dt][3] * i3);
  }
}

// ---------------- loss ----------------
__global__ void zero_one(float* __restrict__ p) {
  if (blockIdx.x == 0 && threadIdx.x == 0) *p = 0.f;
}

__global__ __launch_bounds__(256) void loss_kernel(const float* __restrict__ logits,
                                                   const int* __restrict__ targets,
                                                   float* __restrict__ loss) {
  int row = blockIdx.x;
  int tid = threadIdx.x;
  const float* lg = logits + (size_t)row * Vc;
  float m = -1e30f;
  for (int v = tid; v < Vc; v += 256) m = fmaxf(m, lg[v]);
  __shared__ float red[256];
  red[tid] = m;
  __syncthreads();
  for (int off = 128; off > 0; off >>= 1) {
    if (tid < off) red[tid] = fmaxf(red[tid], red[tid + off]);
    __syncthreads();
  }
  m = red[0];
  __syncthreads();
  float s = 0.f;
  for (int v = tid; v < Vc; v += 256) s += __expf(lg[v] - m);
  red[tid] = s;
  __syncthreads();
  for (int off = 128; off > 0; off >>= 1) {
    if (tid < off) red[tid] += red[tid + off];
    __syncthreads();
  }
  if (tid == 0) {
    float lse = logf(red[0]) + m;
    float lt = lg[targets[row]];
    atomicAdd(loss, (lse - lt) * (1.0f / BTc));
  }
}

// ---------------- launch ----------------
extern "C" void kernel_launch(void* const* d_in, const int* in_sizes, int n_in,
                              void* d_out, int out_size, void* d_ws, size_t ws_size,
                              hipStream_t stream) {
  const int*   idx     = (const int*)d_in[0];
  const int*   targets = (const int*)d_in[1];
  const float* tok_emb = (const float*)d_in[2];
  const float* pos_emb = (const float*)d_in[3];
  const float* Wq = (const float*)d_in[4];
  const float* bq = (const float*)d_in[5];
  const float* Wk = (const float*)d_in[6];
  const float* bk = (const float*)d_in[7];
  const float* Wv = (const float*)d_in[8];
  const float* bv = (const float*)d_in[9];
  const float* Wo = (const float*)d_in[10];
  const float* bo = (const float*)d_in[11];
  const float* ln1_g = (const float*)d_in[12];
  const float* ln1_b = (const float*)d_in[13];
  const float* W1 = (const float*)d_in[14];
  const float* b1 = (const float*)d_in[15];
  const float* W2 = (const float*)d_in[16];
  const float* b2 = (const float*)d_in[17];
  const float* ln2_g = (const float*)d_in[18];
  const float* ln2_b = (const float*)d_in[19];
  const float* lnf_g = (const float*)d_in[20];
  const float* lnf_b = (const float*)d_in[21];
  const float* Wlm = (const float*)d_in[22];
  const float* blm = (const float*)d_in[23];
  float* out = (float*)d_out;

  // ---- workspace layout (91.3 MB) ----
  char* p = (char*)d_ws;
  u16* actb = (u16*)p;  p += (size_t)BTc * Ec * 2;        //  3,145,728
  float* bp = (float*)p; p += (size_t)Lc * QKVW * 4;      //     36,864
  u16* vtb  = (u16*)p;  p += (size_t)Bc * Hc * HSc * Tc * 2;  // 3,145,728
  char* region = p;                                       // 84,934,656 reusable
  float* x    = (float*)(region);                         //  6,291,456
  u16* qkvb   = (u16*)(region + 6291456);                 //  9,437,184
  u16* mlphb  = (u16*)(region + 15728640);                // 12,582,912
  u16* wqkvp  = (u16*)(region + 28311552);                // 14,155,776
  u16* wop    = (u16*)(region + 42467328);                //  4,718,592
  u16* w1p    = (u16*)(region + 47185920);                // 18,874,368
  u16* w2p    = (u16*)(region + 66060288);                // 18,874,368
  u16* wlmp   = (u16*)(region);                           // 49,152,000 ALIAS (post-layers)

  // weight repack (bf16, transposed to [N][K]) — all except Wlm (deferred)
  repack_qkv_bf16<<<dim3(2, 24, Lc * 3 * Hc), 256, 0, stream>>>(Wq, Wk, Wv, wqkvp);
  repack_bqkv<<<(Lc * QKVW + 255) / 256, 256, 0, stream>>>(bq, bk, bv, bp);
  transpose_cast<<<dim3(Ec / 32, Ec / 32, Lc), 256, 0, stream>>>(Wo, wop, Ec, Ec);
  transpose_cast<<<dim3(4 * Ec / 32, Ec / 32, Lc), 256, 0, stream>>>(W1, w1p, Ec, 4 * Ec);
  transpose_cast<<<dim3(Ec / 32, 4 * Ec / 32, Lc), 256, 0, stream>>>(W2, w2p, 4 * Ec, Ec);

  // embedding
  embed_kernel<<<(BTc * (Ec / 4) + 255) / 256, 256, 0, stream>>>(idx, tok_emb, pos_emb, x);

  for (int l = 0; l < Lc; l++) {
    ln_kernel<<<BTc, 256, 0, stream>>>(x, ln1_g + l * Ec, ln1_b + l * Ec, actb);
    gemm_bf16<3><<<dim3(QKVW / 128, BTc / 128), 256, 0, stream>>>(
        actb, wqkvp + (size_t)l * Ec * QKVW, bp + l * QKVW, nullptr, qkvb, BTc, QKVW, Ec);
    vtrans<<<dim3(Tc / 64, Bc * Hc), 256, 0, stream>>>(qkvb, vtb);
    attn_mfma<<<dim3(Bc * Hc, Tc / 64), 256, 0, stream>>>(qkvb, vtb, actb);
    gemm_bf16<2><<<dim3(Ec / 128, BTc / 128), 256, 0, stream>>>(
        actb, wop + (size_t)l * Ec * Ec, bo + l * Ec, x, x, BTc, Ec, Ec);
    ln_kernel<<<BTc, 256, 0, stream>>>(x, ln2_g + l * Ec, ln2_b + l * Ec, actb);
    gemm_bf16<1><<<dim3(4 * Ec / 128, BTc / 128), 256, 0, stream>>>(
        actb, w1p + (size_t)l * Ec * 4 * Ec, b1 + l * 4 * Ec, nullptr, mlphb, BTc, 4 * Ec, Ec);
    gemm_bf16<2><<<dim3(Ec / 128, BTc / 128), 256, 0, stream>>>(
        mlphb, w2p + (size_t)l * 4 * Ec * Ec, b2 + l * Ec, x, x, BTc, Ec, 4 * Ec);
  }

  // final LN (consumes x) -> then Wlm repack may overwrite region
  ln_kernel<<<BTc, 256, 0, stream>>>(x, lnf_g, lnf_b, actb);
  transpose_cast<<<dim3(Vc / 32, Ec / 32, 1), 256, 0, stream>>>(Wlm, wlmp, Ec, Vc);
  gemm_bf16<0><<<dim3(Vc / 128, BTc / 128), 256, 0, stream>>>(
      actb, wlmp, blm, nullptr, out, BTc, Vc, Ec);

  // loss
  zero_one<<<1, 64, 0, stream>>>(out + NLOGITS);
  loss_kernel<<<BTc, 256, 0, stream>>>(out, targets, out + NLOGITS);
}

// Round 5
// 1435.900 us; speedup vs baseline: 6.5497x; 1.0672x over previous
//
#include <hip/hip_runtime.h>
#include <math.h>

// GPT forward: L=4, H=12, E=768, HS=64, V=32000, B=2, T=1024
// Output: logits [2,1024,32000] f32 then loss scalar at d_out[65536000].
//
// Workspace (91.3 MB): actb 3.1M | bp 37K | vt 3.1M | region 84.9M
//   region: x f32 | qkvb bf16 | mlphb bf16 | wqkvp | wop | w1p | w2p
//   wlmp (49.2M) ALIASES region front (built only after layers finish).

typedef unsigned short u16;
typedef short v8s __attribute__((ext_vector_type(8)));   // 8 bf16 (MFMA A/B frag)
typedef float v4f __attribute__((ext_vector_type(4)));   // MFMA accumulator

constexpr int Lc = 4, Hc = 12, Ec = 768, HSc = 64, Vc = 32000, Bc = 2, Tc = 1024;
constexpr int BTc = Bc * Tc;               // 2048
constexpr int QKVW = 3 * Ec;               // 2304
constexpr size_t NLOGITS = (size_t)BTc * Vc;

__device__ inline u16 f2bf(float f) {
  unsigned u = __builtin_bit_cast(unsigned, f);
  u += 0x7fff + ((u >> 16) & 1);
  return (u16)(u >> 16);
}
__device__ inline float bf2f(u16 u) {
  return __builtin_bit_cast(float, (unsigned)u << 16);
}

__device__ inline void gload16(const void* g, void* l) {
  __builtin_amdgcn_global_load_lds(
      (const __attribute__((address_space(1))) void*)g,
      (__attribute__((address_space(3))) void*)l, 16, 0, 0);
}

#define MFMA16(a, b, c) __builtin_amdgcn_mfma_f32_16x16x32_bf16((a), (b), (c), 0, 0, 0)

// ---------------- weight repack: transpose + cast to bf16 [N][K] ----------------
__global__ __launch_bounds__(256) void transpose_cast(const float* __restrict__ src,
                                                      u16* __restrict__ dst,
                                                      int R, int C) {
  __shared__ float t[32][33];
  const float* s = src + (size_t)blockIdx.z * R * C;
  u16* d = dst + (size_t)blockIdx.z * R * C;
  int c0 = blockIdx.x * 32, r0 = blockIdx.y * 32;
  int tx = threadIdx.x & 31, ty = threadIdx.x >> 5;  // ty 0..7
#pragma unroll
  for (int i = 0; i < 32; i += 8)
    t[ty + i][tx] = s[(size_t)(r0 + ty + i) * C + c0 + tx];
  __syncthreads();
#pragma unroll
  for (int i = 0; i < 32; i += 8)
    d[(size_t)(c0 + ty + i) * R + r0 + tx] = f2bf(t[tx][ty + i]);
}

// QKV: [L][H][E][HS] (x3) -> bf16 [L][N=2304][K=768], n = part*768 + h*64 + hs
__global__ __launch_bounds__(256) void repack_qkv_bf16(const float* __restrict__ Wq,
                                                       const float* __restrict__ Wk,
                                                       const float* __restrict__ Wv,
                                                       u16* __restrict__ dst) {
  __shared__ float t[32][33];
  int z = blockIdx.z;                       // l*36 + part*12 + h
  int l = z / 36, part = (z / 12) % 3, h = z % 12;
  const float* W = (part == 0) ? Wq : (part == 1) ? Wk : Wv;
  const float* s = W + ((size_t)l * Hc + h) * Ec * HSc;   // [768][64]
  int hs0 = blockIdx.x * 32, k0 = blockIdx.y * 32;
  int tx = threadIdx.x & 31, ty = threadIdx.x >> 5;
#pragma unroll
  for (int i = 0; i < 32; i += 8)
    t[ty + i][tx] = s[(size_t)(k0 + ty + i) * HSc + hs0 + tx];
  __syncthreads();
  u16* drow = dst + ((size_t)l * QKVW + part * Ec + h * 64) * Ec;
#pragma unroll
  for (int i = 0; i < 32; i += 8)
    drow[(size_t)(hs0 + ty + i) * Ec + k0 + tx] = f2bf(t[tx][ty + i]);
}

__global__ void repack_bqkv(const float* __restrict__ bq, const float* __restrict__ bk,
                            const float* __restrict__ bv, float* __restrict__ bp) {
  int i = blockIdx.x * 256 + threadIdx.x;
  if (i >= Lc * QKVW) return;
  int col = i % QKVW;
  int l = i / QKVW;
  float v;
  if (col < Ec) v = bq[l * Ec + col];
  else if (col < 2 * Ec) v = bk[l * Ec + col - Ec];
  else v = bv[l * Ec + col - 2 * Ec];
  bp[i] = v;
}

// ---------------- per-layer V transpose: qkvb V-part -> vt[bh][d][t] bf16 ----------------
__global__ __launch_bounds__(256) void vtrans(const u16* __restrict__ qkvb,
                                              u16* __restrict__ vt) {
  __shared__ u16 tile[64][72];
  const int t0 = blockIdx.x * 64;
  const int bh = blockIdx.y;
  const int b = bh / Hc, h = bh % Hc;
  const int tid = threadIdx.x;
#pragma unroll
  for (int r = 0; r < 2; r++) {
    int idx = r * 256 + tid;
    int t = idx >> 3, dc = idx & 7;
    *(v8s*)&tile[t][dc * 8] =
        *(const v8s*)(qkvb + (size_t)(b * Tc + t0 + t) * QKVW + 2 * Ec + h * 64 + dc * 8);
  }
  __syncthreads();
#pragma unroll
  for (int r = 0; r < 4; r++) {
    int idx = r * 256 + tid;
    int d = idx >> 4, tc = idx & 15;
    unsigned lo = (unsigned)tile[tc * 4 + 0][d] | ((unsigned)tile[tc * 4 + 1][d] << 16);
    unsigned hi = (unsigned)tile[tc * 4 + 2][d] | ((unsigned)tile[tc * 4 + 3][d] << 16);
    uint2 w; w.x = lo; w.y = hi;
    *(uint2*)(vt + (size_t)bh * HSc * Tc + (size_t)d * Tc + t0 + tc * 4) = w;
  }
}

// ---------------- embedding ----------------
__global__ void embed_kernel(const int* __restrict__ idx, const float* __restrict__ tok,
                             const float* __restrict__ pos, float* __restrict__ x) {
  int i = blockIdx.x * 256 + threadIdx.x;
  if (i >= BTc * (Ec / 4)) return;
  int row = i / (Ec / 4);
  int e4 = i % (Ec / 4);
  int t = row & (Tc - 1);
  int token = idx[row];
  float4 a = ((const float4*)(tok + (size_t)token * Ec))[e4];
  float4 b = ((const float4*)(pos + (size_t)t * Ec))[e4];
  float4 o;
  o.x = a.x + b.x; o.y = a.y + b.y; o.z = a.z + b.z; o.w = a.w + b.w;
  ((float4*)(x + (size_t)row * Ec))[e4] = o;
}

// ---------------- layernorm (row = 768), f32 in -> bf16 out ----------------
__global__ __launch_bounds__(256) void ln_kernel(const float* __restrict__ in,
                                                 const float* __restrict__ g,
                                                 const float* __restrict__ b,
                                                 u16* __restrict__ out) {
  int row = blockIdx.x;
  int tid = threadIdx.x;
  const float* xr = in + (size_t)row * Ec;
  float v0 = xr[tid], v1 = xr[tid + 256], v2 = xr[tid + 512];
  float s = v0 + v1 + v2;
  float sq = v0 * v0 + v1 * v1 + v2 * v2;
  __shared__ float rs[256], rq[256];
  rs[tid] = s; rq[tid] = sq;
  __syncthreads();
  for (int off = 128; off > 0; off >>= 1) {
    if (tid < off) { rs[tid] += rs[tid + off]; rq[tid] += rq[tid + off]; }
    __syncthreads();
  }
  float mean = rs[0] * (1.f / Ec);
  float var = rq[0] * (1.f / Ec) - mean * mean;
  float rstd = rsqrtf(var + 1e-5f);
  u16* orow = out + (size_t)row * Ec;
  orow[tid]       = f2bf((v0 - mean) * rstd * g[tid]       + b[tid]);
  orow[tid + 256] = f2bf((v1 - mean) * rstd * g[tid + 256] + b[tid + 256]);
  orow[tid + 512] = f2bf((v2 - mean) * rstd * g[tid + 512] + b[tid + 512]);
}

// ---------------- bf16 MFMA GEMM: C[M,N] = A[M,K] @ Bt[N,K]^T ----------------
// XCD-chunked bijective swizzle (guide T1/m204): each XCD gets a contiguous
// chunk of flat ids decoded m-fastest -> each B n-panel lives in exactly one
// XCD's L2 (fetched once); A (<=3MB) stays L2-resident per XCD.
// MODE 0: bias -> f32; MODE 1: bias+relu -> bf16; MODE 2: bias+res -> f32;
// MODE 3: bias -> bf16.
template <int MODE>
__global__ __launch_bounds__(256) void gemm_bf16(const u16* __restrict__ A,
                                                 const u16* __restrict__ Bt,
                                                 const float* __restrict__ bias,
                                                 const float* __restrict__ Res,
                                                 void* __restrict__ Cout,
                                                 int M, int N, int K) {
  __shared__ __align__(128) char smem[16384];  // A tile 8KB | B tile 8KB
  const int tid = threadIdx.x;
  const int lane = tid & 63, wid = tid >> 6;
  const int wm = wid >> 1, wn = wid & 1;

  // --- block swizzle: dispatch order orig (x-fastest) round-robins XCDs;
  // wgid chunks are contiguous per XCD; decode with m fastest.
  const int nbx = gridDim.x, nby = gridDim.y;
  const int NB = nbx * nby;
  const int orig = blockIdx.y * nbx + blockIdx.x;
  const int q = NB >> 3, r = NB & 7;
  const int x8 = orig & 7, kk8 = orig >> 3;
  const int wgid = (x8 < r ? x8 * (q + 1) : r * (q + 1) + (x8 - r) * q) + kk8;
  const int n0 = (wgid / nby) * 128;
  const int m0 = (wgid % nby) * 128;

  const int rowp0 = wid * 16 + (lane >> 2);
  const int qp = lane & 3;
  const int ql0 = qp ^ ((rowp0 >> 1) & 3);
  const int rowp1 = rowp0 + 64;
  const int ql1 = qp ^ ((rowp1 >> 1) & 3);
  char* ldsA0 = smem + wid * 1024;
  char* ldsA1 = smem + wid * 1024 + 4096;
  char* ldsB0 = smem + 8192 + wid * 1024;
  char* ldsB1 = smem + 8192 + wid * 1024 + 4096;
  const u16* Ag0 = A + (size_t)(m0 + rowp0) * K + ql0 * 8;
  const u16* Ag1 = A + (size_t)(m0 + rowp1) * K + ql1 * 8;
  const u16* Bg0 = Bt + (size_t)(n0 + rowp0) * K + ql0 * 8;
  const u16* Bg1 = Bt + (size_t)(n0 + rowp1) * K + ql1 * 8;

  const int fr = lane & 15, kq = lane >> 4;
  const int rowA = wm * 64 + fr, rowB = wn * 64 + fr;
  const char* ardp = smem + rowA * 64 + (kq ^ ((rowA >> 1) & 3)) * 16;
  const char* brdp = smem + 8192 + rowB * 64 + (kq ^ ((rowB >> 1) & 3)) * 16;

  v4f acc[4][4];
#pragma unroll
  for (int i = 0; i < 4; i++)
#pragma unroll
    for (int j = 0; j < 4; j++) acc[i][j] = (v4f)0.f;

  for (int kt = 0; kt < K; kt += 32) {
    gload16(Ag0 + kt, ldsA0);
    gload16(Ag1 + kt, ldsA1);
    gload16(Bg0 + kt, ldsB0);
    gload16(Bg1 + kt, ldsB1);
    __syncthreads();
    v8s a[4], b[4];
#pragma unroll
    for (int i = 0; i < 4; i++) a[i] = *(const v8s*)(ardp + i * 1024);
#pragma unroll
    for (int i = 0; i < 4; i++) b[i] = *(const v8s*)(brdp + i * 1024);
#pragma unroll
    for (int m = 0; m < 4; m++)
#pragma unroll
      for (int n = 0; n < 4; n++)
        acc[m][n] = MFMA16(a[m], b[n], acc[m][n]);
    __syncthreads();
  }

  const int cRow = m0 + wm * 64 + kq * 4;
  const int cCol = n0 + wn * 64 + fr;
#pragma unroll
  for (int fn = 0; fn < 4; fn++) {
    int col = cCol + fn * 16;
    float bv = bias[col];
#pragma unroll
    for (int fm = 0; fm < 4; fm++) {
#pragma unroll
      for (int j = 0; j < 4; j++) {
        int row = cRow + fm * 16 + j;
        float r2 = acc[fm][fn][j] + bv;
        if (MODE == 2) r2 += Res[(size_t)row * N + col];
        if (MODE == 1) r2 = fmaxf(r2, 0.f);
        if (MODE == 1 || MODE == 3) {
          ((u16*)Cout)[(size_t)row * N + col] = f2bf(r2);
        } else {
          ((float*)Cout)[(size_t)row * N + col] = r2;
        }
      }
    }
  }
}

// ---------------- MFMA flash attention ----------------
// Block = 256 thr = 4 waves; wave w owns 16 queries q0 = by*64 + w*16.
// S^T = K·Q^T from global/L2 (K/V 128KB per (b,h), L2-resident, no staging);
// softmax lane-local; P via wave-private LDS [16][40]; PV from vt[bh][d][t].
__global__ __launch_bounds__(256) void attn_mfma(const u16* __restrict__ qkv,
                                                 const u16* __restrict__ vt,
                                                 u16* __restrict__ out) {
  __shared__ u16 P_all[4][16][40];
  const int bh = blockIdx.x;
  const int b = bh / Hc, h = bh % Hc;
  const int by = (int)gridDim.y - 1 - (int)blockIdx.y;  // heavy tiles first
  const int tid = threadIdx.x;
  const int w = tid >> 6, l = tid & 63;
  const int lr = l & 15, lg = l >> 4;
  const int q0 = by * 64 + w * 16;
  u16 (*P_lds)[40] = P_all[w];

  const u16* qrow = qkv + (size_t)(b * Tc + q0 + lr) * QKVW + h * 64;
  const v8s qf0 = *(const v8s*)(qrow + lg * 8);
  const v8s qf1 = *(const v8s*)(qrow + 32 + lg * 8);

  const u16* kp0 = qkv + (size_t)(b * Tc + lr) * QKVW + Ec + h * 64 + lg * 8;
  const u16* vbase = vt + (size_t)bh * HSc * Tc;

  v4f acc[4];
#pragma unroll
  for (int dt = 0; dt < 4; dt++) acc[dt] = (v4f)0.f;
  float m = -1e30f, lsum = 0.f;
  const float SC = 0.125f;  // 1/sqrt(64)

  const int ntiles = (q0 + 47) >> 5;
  const int nfull = (q0 >= 31) ? ((q0 - 31) >> 5) + 1 : 0;

  for (int kt = 0; kt < ntiles; kt++) {
    const int k0 = kt * 32;
    const u16* ka = kp0 + (size_t)k0 * QKVW;
    const u16* kb = ka + (size_t)16 * QKVW;
    v8s a00 = *(const v8s*)ka;
    v8s a01 = *(const v8s*)(ka + 32);
    v8s a10 = *(const v8s*)kb;
    v8s a11 = *(const v8s*)(kb + 32);
    v4f s0 = (v4f)0.f, s1 = (v4f)0.f;
    s0 = MFMA16(a00, qf0, s0);
    s0 = MFMA16(a01, qf1, s0);
    s1 = MFMA16(a10, qf0, s1);
    s1 = MFMA16(a11, qf1, s1);
    if (kt >= nfull) {
      const int qg = q0 + lr;
#pragma unroll
      for (int j = 0; j < 4; j++) {
        if (k0 + lg * 4 + j > qg) s0[j] = -1e30f;
        if (k0 + 16 + lg * 4 + j > qg) s1[j] = -1e30f;
      }
    }
    float mx = fmaxf(fmaxf(fmaxf(s0[0], s0[1]), fmaxf(s0[2], s0[3])),
                     fmaxf(fmaxf(s1[0], s1[1]), fmaxf(s1[2], s1[3])));
    mx = fmaxf(mx, __shfl_xor(mx, 16));
    mx = fmaxf(mx, __shfl_xor(mx, 32));
    const float mn = fmaxf(m, mx);
    const float alpha = __expf((m - mn) * SC);
    float p[8];
#pragma unroll
    for (int j = 0; j < 4; j++) {
      p[j] = __expf((s0[j] - mn) * SC);
      p[4 + j] = __expf((s1[j] - mn) * SC);
    }
    lsum = lsum * alpha + (((p[0] + p[1]) + (p[2] + p[3])) +
                           ((p[4] + p[5]) + (p[6] + p[7])));
    m = mn;
    uint2 w0, w1;
    w0.x = (unsigned)f2bf(p[0]) | ((unsigned)f2bf(p[1]) << 16);
    w0.y = (unsigned)f2bf(p[2]) | ((unsigned)f2bf(p[3]) << 16);
    w1.x = (unsigned)f2bf(p[4]) | ((unsigned)f2bf(p[5]) << 16);
    w1.y = (unsigned)f2bf(p[6]) | ((unsigned)f2bf(p[7]) << 16);
    *(uint2*)&P_lds[lr][lg * 4] = w0;
    *(uint2*)&P_lds[lr][16 + lg * 4] = w1;
    const float al0 = __shfl(alpha, lg * 4 + 0);
    const float al1 = __shfl(alpha, lg * 4 + 1);
    const float al2 = __shfl(alpha, lg * 4 + 2);
    const float al3 = __shfl(alpha, lg * 4 + 3);
    const v8s pa = *(const v8s*)&P_lds[lr][lg * 8];
#pragma unroll
    for (int dt = 0; dt < 4; dt++) {
      v4f t = acc[dt];
      t[0] *= al0; t[1] *= al1; t[2] *= al2; t[3] *= al3;
      const v8s bv = *(const v8s*)(vbase + (size_t)(dt * 16 + lr) * Tc + k0 + lg * 8);
      acc[dt] = MFMA16(pa, bv, t);
    }
  }
  lsum += __shfl_xor(lsum, 16);
  lsum += __shfl_xor(lsum, 32);
  const float inv = 1.f / lsum;
  const float i0 = __shfl(inv, lg * 4 + 0);
  const float i1 = __shfl(inv, lg * 4 + 1);
  const float i2 = __shfl(inv, lg * 4 + 2);
  const float i3 = __shfl(inv, lg * 4 + 3);
  u16* ob = out + (size_t)(b * Tc + q0) * Ec + h * 64;
#pragma unroll
  for (int dt = 0; dt < 4; dt++) {
    ob[(size_t)(lg * 4 + 0) * Ec + dt * 16 + lr] = f2bf(acc[dt][0] * i0);
    ob[(size_t)(lg * 4 + 1) * Ec + dt * 16 + lr] = f2bf(acc[dt][1] * i1);
    ob[(size_t)(lg * 4 + 2) * Ec + dt * 16 + lr] = f2bf(acc[dt][2] * i2);
    ob[(size_t)(lg * 4 + 3) * Ec + dt * 16 + lr] = f2bf(acc[dt][3] * i3);
  }
}

// ---------------- loss ----------------
__global__ void zero_one(float* __restrict__ p) {
  if (blockIdx.x == 0 && threadIdx.x == 0) *p = 0.f;
}

// single-pass online log-sum-exp: one 262MB read instead of two.
__global__ __launch_bounds__(256) void loss_kernel(const float* __restrict__ logits,
                                                   const int* __restrict__ targets,
                                                   float* __restrict__ loss) {
  int row = blockIdx.x;
  int tid = threadIdx.x;
  const float4* lg4 = (const float4*)(logits + (size_t)row * Vc);
  float m = -1e30f, s = 0.f;
  for (int v = tid; v < Vc / 4; v += 256) {
    float4 x = lg4[v];
    float mx = fmaxf(fmaxf(x.x, x.y), fmaxf(x.z, x.w));
    float mn = fmaxf(m, mx);
    s = s * __expf(m - mn) + __expf(x.x - mn) + __expf(x.y - mn)
        + __expf(x.z - mn) + __expf(x.w - mn);
    m = mn;
  }
  __shared__ float rm[256], rsum[256];
  rm[tid] = m; rsum[tid] = s;
  __syncthreads();
  for (int off = 128; off > 0; off >>= 1) {
    if (tid < off) {
      float ma = rm[tid], mb = rm[tid + off];
      float M = fmaxf(ma, mb);
      rsum[tid] = rsum[tid] * __expf(ma - M) + rsum[tid + off] * __expf(mb - M);
      rm[tid] = M;
    }
    __syncthreads();
  }
  if (tid == 0) {
    float lse = logf(rsum[0]) + rm[0];
    float lt = logits[(size_t)row * Vc + targets[row]];
    atomicAdd(loss, (lse - lt) * (1.0f / BTc));
  }
}

// ---------------- launch ----------------
extern "C" void kernel_launch(void* const* d_in, const int* in_sizes, int n_in,
                              void* d_out, int out_size, void* d_ws, size_t ws_size,
                              hipStream_t stream) {
  const int*   idx     = (const int*)d_in[0];
  const int*   targets = (const int*)d_in[1];
  const float* tok_emb = (const float*)d_in[2];
  const float* pos_emb = (const float*)d_in[3];
  const float* Wq = (const float*)d_in[4];
  const float* bq = (const float*)d_in[5];
  const float* Wk = (const float*)d_in[6];
  const float* bk = (const float*)d_in[7];
  const float* Wv = (const float*)d_in[8];
  const float* bv = (const float*)d_in[9];
  const float* Wo = (const float*)d_in[10];
  const float* bo = (const float*)d_in[11];
  const float* ln1_g = (const float*)d_in[12];
  const float* ln1_b = (const float*)d_in[13];
  const float* W1 = (const float*)d_in[14];
  const float* b1 = (const float*)d_in[15];
  const float* W2 = (const float*)d_in[16];
  const float* b2 = (const float*)d_in[17];
  const float* ln2_g = (const float*)d_in[18];
  const float* ln2_b = (const float*)d_in[19];
  const float* lnf_g = (const float*)d_in[20];
  const float* lnf_b = (const float*)d_in[21];
  const float* Wlm = (const float*)d_in[22];
  const float* blm = (const float*)d_in[23];
  float* out = (float*)d_out;

  // ---- workspace layout (91.3 MB) ----
  char* p = (char*)d_ws;
  u16* actb = (u16*)p;  p += (size_t)BTc * Ec * 2;        //  3,145,728
  float* bp = (float*)p; p += (size_t)Lc * QKVW * 4;      //     36,864
  u16* vtb  = (u16*)p;  p += (size_t)Bc * Hc * HSc * Tc * 2;  // 3,145,728
  char* region = p;                                       // 84,934,656 reusable
  float* x    = (float*)(region);                         //  6,291,456
  u16* qkvb   = (u16*)(region + 6291456);                 //  9,437,184
  u16* mlphb  = (u16*)(region + 15728640);                // 12,582,912
  u16* wqkvp  = (u16*)(region + 28311552);                // 14,155,776
  u16* wop    = (u16*)(region + 42467328);                //  4,718,592
  u16* w1p    = (u16*)(region + 47185920);                // 18,874,368
  u16* w2p    = (u16*)(region + 66060288);                // 18,874,368
  u16* wlmp   = (u16*)(region);                           // 49,152,000 ALIAS (post-layers)

  // weight repack (bf16, transposed to [N][K]) — all except Wlm (deferred)
  repack_qkv_bf16<<<dim3(2, 24, Lc * 3 * Hc), 256, 0, stream>>>(Wq, Wk, Wv, wqkvp);
  repack_bqkv<<<(Lc * QKVW + 255) / 256, 256, 0, stream>>>(bq, bk, bv, bp);
  transpose_cast<<<dim3(Ec / 32, Ec / 32, Lc), 256, 0, stream>>>(Wo, wop, Ec, Ec);
  transpose_cast<<<dim3(4 * Ec / 32, Ec / 32, Lc), 256, 0, stream>>>(W1, w1p, Ec, 4 * Ec);
  transpose_cast<<<dim3(Ec / 32, 4 * Ec / 32, Lc), 256, 0, stream>>>(W2, w2p, 4 * Ec, Ec);

  // embedding
  embed_kernel<<<(BTc * (Ec / 4) + 255) / 256, 256, 0, stream>>>(idx, tok_emb, pos_emb, x);

  for (int l = 0; l < Lc; l++) {
    ln_kernel<<<BTc, 256, 0, stream>>>(x, ln1_g + l * Ec, ln1_b + l * Ec, actb);
    gemm_bf16<3><<<dim3(QKVW / 128, BTc / 128), 256, 0, stream>>>(
        actb, wqkvp + (size_t)l * Ec * QKVW, bp + l * QKVW, nullptr, qkvb, BTc, QKVW, Ec);
    vtrans<<<dim3(Tc / 64, Bc * Hc), 256, 0, stream>>>(qkvb, vtb);
    attn_mfma<<<dim3(Bc * Hc, Tc / 64), 256, 0, stream>>>(qkvb, vtb, actb);
    gemm_bf16<2><<<dim3(Ec / 128, BTc / 128), 256, 0, stream>>>(
        actb, wop + (size_t)l * Ec * Ec, bo + l * Ec, x, x, BTc, Ec, Ec);
    ln_kernel<<<BTc, 256, 0, stream>>>(x, ln2_g + l * Ec, ln2_b + l * Ec, actb);
    gemm_bf16<1><<<dim3(4 * Ec / 128, BTc / 128), 256, 0, stream>>>(
        actb, w1p + (size_t)l * Ec * 4 * Ec, b1 + l * 4 * Ec, nullptr, mlphb, BTc, 4 * Ec, Ec);
    gemm_bf16<2><<<dim3(Ec / 128, BTc / 128), 256, 0, stream>>>(
        mlphb, w2p + (size_t)l * 4 * Ec * Ec, b2 + l * Ec, x, x, BTc, Ec, 4 * Ec);
  }

  // final LN (consumes x) -> then Wlm repack may overwrite region
  ln_kernel<<<BTc, 256, 0, stream>>>(x, lnf_g, lnf_b, actb);
  transpose_cast<<<dim3(Vc / 32, Ec / 32, 1), 256, 0, stream>>>(Wlm, wlmp, Ec, Vc);
  gemm_bf16<0><<<dim3(Vc / 128, BTc / 128), 256, 0, stream>>>(
      actb, wlmp, blm, nullptr, out, BTc, Vc, Ec);

  // loss
  zero_one<<<1, 64, 0, stream>>>(out + NLOGITS);
  loss_kernel<<<BTc, 256, 0, stream>>>(out, targets, out + NLOGITS);
}